// Round 1
// baseline (1230.561 us; speedup 1.0000x reference)
//
#include <hip/hip_runtime.h>
#include <stdint.h>

#define E_ 64
#define KTOP 4
#define H_ 2048
#define I_ 1536
#define GS_ 128
#define T_ 1024
#define CAP 128

typedef __attribute__((ext_vector_type(8))) short short8;
typedef __attribute__((ext_vector_type(4))) float f32x4;

__device__ __forceinline__ uint32_t bf16rne(float f) {
  uint32_t u = __float_as_uint(f);
  return (u + 0x7FFFu + ((u >> 16) & 1u)) >> 16;
}
__device__ __forceinline__ float bf16f(uint32_t b) {
  return __uint_as_float(b << 16);
}

// ---------------- cast x (f32 -> bf16) ----------------
__global__ void cast_x_kernel(const float* __restrict__ x, uint16_t* __restrict__ xb, int n4) {
  int i = blockIdx.x * blockDim.x + threadIdx.x;
  if (i >= n4) return;
  float4 v = ((const float4*)x)[i];
  uint32_t lo = bf16rne(v.x) | (bf16rne(v.y) << 16);
  uint32_t hi = bf16rne(v.z) | (bf16rne(v.w) << 16);
  uint2 r; r.x = lo; r.y = hi;
  ((uint2*)xb)[i] = r;
}

// ---------------- routing: logits, top-4, weights ----------------
__global__ __launch_bounds__(256) void routing_kernel(
    const float* __restrict__ x, const float* __restrict__ gw,
    float* __restrict__ tw, int* __restrict__ ti) {
  int t = blockIdx.x;
  int tid = threadIdx.x;
  int e = tid >> 2, ch = tid & 3;
  const float4* xp = (const float4*)(x + (long)t * H_ + ch * 512);
  const float4* gp = (const float4*)(gw + (long)e * H_ + ch * 512);
  float acc = 0.f;
#pragma unroll 4
  for (int i = 0; i < 128; i++) {
    float4 a = xp[i], b = gp[i];
    acc += a.x * b.x + a.y * b.y + a.z * b.z + a.w * b.w;
  }
  acc += __shfl_xor(acc, 1);
  acc += __shfl_xor(acc, 2);
  __shared__ float lg[E_];
  if (ch == 0) lg[e] = acc;
  __syncthreads();
  if (tid < 64) {
    int lane = tid;
    float v = lg[lane];
    float vals[KTOP]; int ids[KTOP];
#pragma unroll
    for (int k = 0; k < KTOP; k++) {
      float bv = v; int bi = lane;
      for (int off = 32; off; off >>= 1) {
        float ov = __shfl_xor(bv, off);
        int oi = __shfl_xor(bi, off);
        if (ov > bv || (ov == bv && oi < bi)) { bv = ov; bi = oi; }
      }
      vals[k] = bv; ids[k] = bi;
      if (lane == bi) v = -3.4e38f;
    }
    if (lane == 0) {
      float m = vals[0];
      float p[KTOP]; float s = 0.f;
#pragma unroll
      for (int k = 0; k < KTOP; k++) { p[k] = expf(vals[k] - m); s += p[k]; }
      float inv = 1.f / s;
#pragma unroll
      for (int k = 0; k < KTOP; k++) {
        tw[t * KTOP + k] = p[k] * inv;
        ti[t * KTOP + k] = ids[k];
      }
    }
  }
}

// ---------------- dispatch: stable rank-within-expert + capacity ----------------
__global__ void assign_kernel(const int* __restrict__ ti, int* __restrict__ counts,
                              int* __restrict__ tlist, int* __restrict__ slot_of) {
  int e = blockIdx.x;
  int lane = threadIdx.x;  // 64
  int cnt = 0;
  for (int base = 0; base < T_ * KTOP; base += 64) {
    int a = base + lane;
    int ef = ti[a];
    unsigned long long m = __ballot(ef == e);
    if (ef == e) {
      int rank = cnt + __popcll(m & ((1ull << lane) - 1ull));
      if (rank < CAP) {
        tlist[e * CAP + rank] = a >> 2;
        slot_of[a] = e * CAP + rank;
      } else {
        slot_of[a] = -1;
      }
    }
    cnt += __popcll(m);
  }
  if (lane == 0) counts[e] = min(cnt, CAP);
}

// ---------------- generic FP4-dequant GEMM ----------------
// out[row_base+m, bn*128+n] = sum_k A[rowid(m), k] * W[n, k],
// W[n,k] = fp4(packed[n, k/8] nibble k%8) * scales[k/GS, n]
// tiles: M=64, N=128, BK=128 (= GS). 256 threads = 4 waves (2x2), wave tile 32x64.
template <int OUTF32>
__global__ __launch_bounds__(256, 3) void gemm_fp4_kernel(
    const uint16_t* __restrict__ A, int ldA,
    const int* __restrict__ rowids, const int* __restrict__ counts,
    const int* __restrict__ packed, long p_stride,
    const float* __restrict__ scales, long s_stride,
    void* __restrict__ outp, int K, int N, int row_stride_e) {
  __shared__ uint16_t As[64 * 128];   // 16 KB
  __shared__ uint16_t Bs[128 * 128];  // 32 KB
  __shared__ int rowid_s[64];

  int e = blockIdx.z, mb = blockIdx.y, bn = blockIdx.x;
  int tid = threadIdx.x;
  int wave = tid >> 6, lane = tid & 63;

  int row_base = e * row_stride_e + mb * 64;
  int valid = 64;
  if (counts) {
    valid = counts[e] - mb * 64;
    if (valid <= 0) return;
    if (valid > 64) valid = 64;
  }
  if (tid < 64) {
    int rr = tid < valid ? tid : valid - 1;
    rowid_s[tid] = rowids ? rowids[row_base + rr] : row_base + rr;
  }

  const int* packed_e = packed + (long)e * p_stride;
  const float* scales_e = scales + (long)e * s_stride;

  int j = tid >> 1;        // B tile row (n)
  int wseg = tid & 1;      // which 8-word half of the 16-word row segment
  int n_col = bn * 128 + j;
  const int* prow = packed_e + (long)n_col * (K >> 3) + wseg * 8;

  f32x4 acc[2][4];
#pragma unroll
  for (int a0 = 0; a0 < 2; a0++)
#pragma unroll
    for (int b0 = 0; b0 < 4; b0++) {
      f32x4 z = {0.f, 0.f, 0.f, 0.f};
      acc[a0][b0] = z;
    }

  int wm = wave >> 1, wn = wave & 1;
  int q4 = (lane >> 4) << 3;  // lane's k-chunk offset
  int r16 = lane & 15;

  __syncthreads();  // rowid_s visible

  for (int kt = 0; kt < K; kt += 128) {
    // ---- stage A tile (64 rows x 128 k, bf16) via async global->LDS, 16B/lane
#pragma unroll
    for (int ii = 0; ii < 4; ii++) {
      int inst = wave * 4 + ii;
      int r = inst * 4 + (lane >> 4);
      const uint16_t* src = A + (long)rowid_s[r] * ldA + kt + ((lane & 15) << 3);
      __builtin_amdgcn_global_load_lds(
          (const __attribute__((address_space(1))) unsigned int*)src,
          (__attribute__((address_space(3))) unsigned int*)(As + inst * 512),
          16, 0, 0);
    }
    // ---- stage B tile: load 8 packed words, dequant via scaled byte-LUT + v_perm
    {
      float s = scales_e[(long)(kt >> 7) * N + n_col];
      uint32_t b1 = bf16rne(s), b15 = bf16rne(1.5f * s);
      uint32_t t0 = 0, t1 = b1 - 0x80, t2 = b1, t3 = b15;
      uint32_t t4 = b1 + 0x80, t5 = b15 + 0x80, t6 = b1 + 0x100, t7 = b15 + 0x100;
      uint32_t tll = (t0 & 0xFF) | ((t1 & 0xFF) << 8) | ((t2 & 0xFF) << 16) | ((t3 & 0xFF) << 24);
      uint32_t tlh = (t4 & 0xFF) | ((t5 & 0xFF) << 8) | ((t6 & 0xFF) << 16) | ((t7 & 0xFF) << 24);
      uint32_t thl = (t0 >> 8) | ((t1 >> 8) << 8) | ((t2 >> 8) << 16) | ((t3 >> 8) << 24);
      uint32_t thh = (t4 >> 8) | ((t5 >> 8) << 8) | ((t6 >> 8) << 16) | ((t7 >> 8) << 24);

      const int4* pv = (const int4*)(prow + (kt >> 3));
      int4 wA = pv[0];
      int4 wB = pv[1];
      uint32_t wsv[8] = {(uint32_t)wA.x, (uint32_t)wA.y, (uint32_t)wA.z, (uint32_t)wA.w,
                         (uint32_t)wB.x, (uint32_t)wB.y, (uint32_t)wB.z, (uint32_t)wB.w};
      uint16_t* bdst = Bs + j * 128 + wseg * 64;
#pragma unroll
      for (int i = 0; i < 8; i++) {
        uint32_t w = wsv[i];
        uint32_t ev = w & 0x07070707u;         // mags of nibbles 0,2,4,6
        uint32_t od = (w >> 4) & 0x07070707u;  // mags of nibbles 1,3,5,7
        uint32_t se = (w << 4) & 0x80808080u;  // signs (even) -> bit7 of byte
        uint32_t so = w & 0x80808080u;         // signs (odd)
        uint32_t he = __builtin_amdgcn_perm(thh, thl, ev) | se;
        uint32_t ho = __builtin_amdgcn_perm(thh, thl, od) | so;
        uint32_t le = __builtin_amdgcn_perm(tlh, tll, ev);
        uint32_t lo = __builtin_amdgcn_perm(tlh, tll, od);
        uint32_t v02 = __builtin_amdgcn_perm(he, le, 0x05010400u);  // bf16(n0),bf16(n2)
        uint32_t v46 = __builtin_amdgcn_perm(he, le, 0x07030602u);  // bf16(n4),bf16(n6)
        uint32_t v13 = __builtin_amdgcn_perm(ho, lo, 0x05010400u);  // bf16(n1),bf16(n3)
        uint32_t v57 = __builtin_amdgcn_perm(ho, lo, 0x07030602u);  // bf16(n5),bf16(n7)
        uint4 q;
        q.x = __builtin_amdgcn_perm(v13, v02, 0x05040100u);  // n0,n1
        q.y = __builtin_amdgcn_perm(v13, v02, 0x07060302u);  // n2,n3
        q.z = __builtin_amdgcn_perm(v57, v46, 0x05040100u);  // n4,n5
        q.w = __builtin_amdgcn_perm(v57, v46, 0x07060302u);  // n6,n7
        *(uint4*)(bdst + i * 8) = q;
      }
    }
    __syncthreads();

    // ---- MFMA compute
    const uint16_t* abase = As + (wm * 32) * 128;
    const uint16_t* bbase = Bs + (wn * 64) * 128;
#pragma unroll
    for (int kk = 0; kk < 128; kk += 32) {
      short8 af[2], bfr[4];
#pragma unroll
      for (int fm = 0; fm < 2; fm++)
        af[fm] = *(const short8*)(abase + (fm * 16 + r16) * 128 + kk + q4);
#pragma unroll
      for (int fn = 0; fn < 4; fn++)
        bfr[fn] = *(const short8*)(bbase + (fn * 16 + r16) * 128 + kk + q4);
#pragma unroll
      for (int fm = 0; fm < 2; fm++)
#pragma unroll
        for (int fn = 0; fn < 4; fn++)
          acc[fm][fn] = __builtin_amdgcn_mfma_f32_16x16x32_bf16(af[fm], bfr[fn], acc[fm][fn], 0, 0, 0);
    }
    __syncthreads();
  }

  // ---- epilogue: D mapping col=lane&15, row=(lane>>4)*4+reg (m89/m91-verified)
  int outr0 = row_base + wm * 32 + ((lane >> 4) << 2);
  int outc0 = bn * 128 + wn * 64 + (lane & 15);
#pragma unroll
  for (int fm = 0; fm < 2; fm++)
#pragma unroll
    for (int fn = 0; fn < 4; fn++) {
#pragma unroll
      for (int r = 0; r < 4; r++) {
        long row = outr0 + fm * 16 + r;
        long col = outc0 + fn * 16;
        float vv = acc[fm][fn][r];
        if (OUTF32) ((float*)outp)[row * N + col] = vv;
        else ((uint16_t*)outp)[row * N + col] = (uint16_t)bf16rne(vv);
      }
    }
}

// ---------------- h = silu(g) * u  (bf16, elementwise x8) ----------------
__global__ void silu_mul_kernel(const uint16_t* __restrict__ g, const uint16_t* __restrict__ u,
                                uint16_t* __restrict__ h, int n8) {
  int i = blockIdx.x * blockDim.x + threadIdx.x;
  if (i >= n8) return;
  uint4 gv = ((const uint4*)g)[i];
  uint4 uv = ((const uint4*)u)[i];
  uint32_t gw[4] = {gv.x, gv.y, gv.z, gv.w};
  uint32_t uw[4] = {uv.x, uv.y, uv.z, uv.w};
  uint32_t rw[4];
#pragma unroll
  for (int w = 0; w < 4; w++) {
    float g0 = bf16f(gw[w] & 0xFFFFu), g1 = bf16f(gw[w] >> 16);
    float u0 = bf16f(uw[w] & 0xFFFFu), u1 = bf16f(uw[w] >> 16);
    float r0 = g0 / (1.f + __expf(-g0)) * u0;
    float r1 = g1 / (1.f + __expf(-g1)) * u1;
    rw[w] = bf16rne(r0) | (bf16rne(r1) << 16);
  }
  uint4 res; res.x = rw[0]; res.y = rw[1]; res.z = rw[2]; res.w = rw[3];
  ((uint4*)h)[i] = res;
}

// ---------------- combine: y[t] += sum_k w_k * eout[slot_k] ----------------
__global__ __launch_bounds__(256) void combine_kernel(
    float* __restrict__ y, const uint16_t* __restrict__ eout,
    const int* __restrict__ slot_of, const float* __restrict__ tw) {
  int t = blockIdx.x;
  int c = threadIdx.x * 8;
  float* yp = y + (long)t * H_ + c;
  float4 y0 = ((float4*)yp)[0];
  float4 y1 = ((float4*)yp)[1];
  float a[8] = {y0.x, y0.y, y0.z, y0.w, y1.x, y1.y, y1.z, y1.w};
#pragma unroll
  for (int k = 0; k < KTOP; k++) {
    int s = slot_of[t * KTOP + k];
    float w = tw[t * KTOP + k];
    if (s < 0) continue;
    uint4 v = *(const uint4*)(eout + (long)s * H_ + c);
    uint32_t vw[4] = {v.x, v.y, v.z, v.w};
#pragma unroll
    for (int jj = 0; jj < 4; jj++) {
      a[2 * jj]     += w * bf16f(vw[jj] & 0xFFFFu);
      a[2 * jj + 1] += w * bf16f(vw[jj] >> 16);
    }
  }
  float4 o0 = {a[0], a[1], a[2], a[3]};
  float4 o1 = {a[4], a[5], a[6], a[7]};
  ((float4*)yp)[0] = o0;
  ((float4*)yp)[1] = o1;
}

extern "C" void kernel_launch(void* const* d_in, const int* in_sizes, int n_in,
                              void* d_out, int out_size, void* d_ws, size_t ws_size,
                              hipStream_t stream) {
  const float* x              = (const float*)d_in[0];
  const float* gate_w         = (const float*)d_in[1];
  const float* gate_scales    = (const float*)d_in[2];
  const float* up_scales      = (const float*)d_in[3];
  const float* down_scales    = (const float*)d_in[4];
  const float* sh_gate_scales = (const float*)d_in[5];
  const float* sh_up_scales   = (const float*)d_in[6];
  const float* sh_down_scales = (const float*)d_in[7];
  const int* gate_packed      = (const int*)d_in[8];
  const int* up_packed        = (const int*)d_in[9];
  const int* down_packed      = (const int*)d_in[10];
  const int* sh_gate_packed   = (const int*)d_in[11];
  const int* sh_up_packed     = (const int*)d_in[12];
  const int* sh_down_packed   = (const int*)d_in[13];
  float* y = (float*)d_out;

  char* ws = (char*)d_ws;
  uint16_t* xb     = (uint16_t*)(ws);               // 4,194,304 B
  float*    tw     = (float*)(ws + 4194304);        // 16,384
  int*      ti     = (int*)(ws + 4210688);          // 16,384
  int*      counts = (int*)(ws + 4227072);          // 256
  int*      tlist  = (int*)(ws + 4227328);          // 32,768
  int*      slot_of= (int*)(ws + 4260096);          // 16,384
  uint16_t* gbuf   = (uint16_t*)(ws + 4276480);     // 25,165,824 (later h)
  uint16_t* ubuf   = (uint16_t*)(ws + 29442304);    // 25,165,824
  uint16_t* eout   = (uint16_t*)(ws + 29442304);    // 33,554,432 (aliases dead ubuf)
  uint16_t* gsbuf  = (uint16_t*)(ws + 62996736);    // 3,145,728 (later hs)
  uint16_t* usbuf  = (uint16_t*)(ws + 66142464);    // 3,145,728; end ~69.3 MB

  cast_x_kernel<<<2048, 256, 0, stream>>>(x, xb, T_ * H_ / 4);
  routing_kernel<<<T_, 256, 0, stream>>>(x, gate_w, tw, ti);
  assign_kernel<<<E_, 64, 0, stream>>>(ti, counts, tlist, slot_of);

  // expert gate / up : [<=128 tok] x [K=2048] -> [1536]
  gemm_fp4_kernel<0><<<dim3(12, 2, 64), 256, 0, stream>>>(
      xb, H_, tlist, counts, gate_packed, (long)I_ * (H_ / 8), gate_scales, (long)(H_ / GS_) * I_,
      gbuf, H_, I_, CAP);
  gemm_fp4_kernel<0><<<dim3(12, 2, 64), 256, 0, stream>>>(
      xb, H_, tlist, counts, up_packed, (long)I_ * (H_ / 8), up_scales, (long)(H_ / GS_) * I_,
      ubuf, H_, I_, CAP);
  silu_mul_kernel<<<(E_ * CAP * I_ / 8 + 255) / 256, 256, 0, stream>>>(
      gbuf, ubuf, gbuf, E_ * CAP * I_ / 8);
  // expert down : [<=128 tok] x [K=1536] -> [2048]
  gemm_fp4_kernel<0><<<dim3(16, 2, 64), 256, 0, stream>>>(
      gbuf, I_, nullptr, counts, down_packed, (long)H_ * (I_ / 8), down_scales, (long)(I_ / GS_) * H_,
      eout, I_, H_, CAP);

  // shared expert
  gemm_fp4_kernel<0><<<dim3(12, 16, 1), 256, 0, stream>>>(
      xb, H_, nullptr, nullptr, sh_gate_packed, 0, sh_gate_scales, 0,
      gsbuf, H_, I_, 0);
  gemm_fp4_kernel<0><<<dim3(12, 16, 1), 256, 0, stream>>>(
      xb, H_, nullptr, nullptr, sh_up_packed, 0, sh_up_scales, 0,
      usbuf, H_, I_, 0);
  silu_mul_kernel<<<(T_ * I_ / 8 + 255) / 256, 256, 0, stream>>>(
      gsbuf, usbuf, gsbuf, T_ * I_ / 8);
  gemm_fp4_kernel<1><<<dim3(16, 16, 1), 256, 0, stream>>>(
      gsbuf, I_, nullptr, nullptr, sh_down_packed, 0, sh_down_scales, 0,
      y, I_, H_, 0);

  combine_kernel<<<T_, 256, 0, stream>>>(y, eout, slot_of, tw);
}

// Round 2
// 716.789 us; speedup vs baseline: 1.7168x; 1.7168x over previous
//
#include <hip/hip_runtime.h>
#include <stdint.h>

#define E_ 64
#define KTOP 4
#define H_ 2048
#define I_ 1536
#define GS_ 128
#define T_ 1024
#define CAP 128

typedef __attribute__((ext_vector_type(8))) short short8;
typedef __attribute__((ext_vector_type(4))) float f32x4;

__device__ __forceinline__ uint32_t bf16rne(float f) {
  uint32_t u = __float_as_uint(f);
  return (u + 0x7FFFu + ((u >> 16) & 1u)) >> 16;
}
__device__ __forceinline__ float bf16f(uint32_t b) {
  return __uint_as_float(b << 16);
}

// ---------------- cast x (f32 -> bf16) ----------------
__global__ void cast_x_kernel(const float* __restrict__ x, uint16_t* __restrict__ xb, int n4) {
  int i = blockIdx.x * blockDim.x + threadIdx.x;
  if (i >= n4) return;
  float4 v = ((const float4*)x)[i];
  uint32_t lo = bf16rne(v.x) | (bf16rne(v.y) << 16);
  uint32_t hi = bf16rne(v.z) | (bf16rne(v.w) << 16);
  uint2 r; r.x = lo; r.y = hi;
  ((uint2*)xb)[i] = r;
}

// ---------------- routing: logits, top-4, weights ----------------
__global__ __launch_bounds__(256) void routing_kernel(
    const float* __restrict__ x, const float* __restrict__ gw,
    float* __restrict__ tw, int* __restrict__ ti) {
  int t = blockIdx.x;
  int tid = threadIdx.x;
  int e = tid >> 2, ch = tid & 3;
  const float4* xp = (const float4*)(x + (long)t * H_ + ch * 512);
  const float4* gp = (const float4*)(gw + (long)e * H_ + ch * 512);
  float acc = 0.f;
#pragma unroll 4
  for (int i = 0; i < 128; i++) {
    float4 a = xp[i], b = gp[i];
    acc += a.x * b.x + a.y * b.y + a.z * b.z + a.w * b.w;
  }
  acc += __shfl_xor(acc, 1);
  acc += __shfl_xor(acc, 2);
  __shared__ float lg[E_];
  if (ch == 0) lg[e] = acc;
  __syncthreads();
  if (tid < 64) {
    int lane = tid;
    float v = lg[lane];
    float vals[KTOP]; int ids[KTOP];
#pragma unroll
    for (int k = 0; k < KTOP; k++) {
      float bv = v; int bi = lane;
      for (int off = 32; off; off >>= 1) {
        float ov = __shfl_xor(bv, off);
        int oi = __shfl_xor(bi, off);
        if (ov > bv || (ov == bv && oi < bi)) { bv = ov; bi = oi; }
      }
      vals[k] = bv; ids[k] = bi;
      if (lane == bi) v = -3.4e38f;
    }
    if (lane == 0) {
      float m = vals[0];
      float p[KTOP]; float s = 0.f;
#pragma unroll
      for (int k = 0; k < KTOP; k++) { p[k] = expf(vals[k] - m); s += p[k]; }
      float inv = 1.f / s;
#pragma unroll
      for (int k = 0; k < KTOP; k++) {
        tw[t * KTOP + k] = p[k] * inv;
        ti[t * KTOP + k] = ids[k];
      }
    }
  }
}

// ---------------- dispatch: stable rank-within-expert + capacity ----------------
__global__ void assign_kernel(const int* __restrict__ ti, int* __restrict__ counts,
                              int* __restrict__ tlist, int* __restrict__ slot_of) {
  int e = blockIdx.x;
  int lane = threadIdx.x;  // 64
  int cnt = 0;
  for (int base = 0; base < T_ * KTOP; base += 64) {
    int a = base + lane;
    int ef = ti[a];
    unsigned long long m = __ballot(ef == e);
    if (ef == e) {
      int rank = cnt + __popcll(m & ((1ull << lane) - 1ull));
      if (rank < CAP) {
        tlist[e * CAP + rank] = a >> 2;
        slot_of[a] = e * CAP + rank;
      } else {
        slot_of[a] = -1;
      }
    }
    cnt += __popcll(m);
  }
  if (lane == 0) counts[e] = min(cnt, CAP);
}

// ---------------- generic FP4-dequant GEMM ----------------
// out[row_base+m, bn*128+n] = sum_k A[rowid(m), k] * W[n, k],
// W[n,k] = fp4(packed[n, k/8] nibble k%8) * scales[k/GS, n]
// tiles: M=64, N=128, BK=128 (= GS). 256 threads = 4 waves (2x2), wave tile 32x64.
//
// LDS layouts (bank-conflict-free for ds_*_b128):
//  As: row-major 64x128 bf16, but chunk c (16B) of row m holds global k-chunk c^(m&15).
//      (global_load_lds requires lane-contiguous dest; XOR keeps staging coalesced
//       while making fragment reads bank-uniform: group = (kc^r16)%8.)
//  Bs: fragment-order [kc=k/8][n=0..127][8 elems]. Writes: group=n%8; reads: group=r16%8.
template <int OUTF32>
__global__ __launch_bounds__(256, 3) void gemm_fp4_kernel(
    const uint16_t* __restrict__ A, int ldA,
    const int* __restrict__ rowids, const int* __restrict__ counts,
    const int* __restrict__ packed, long p_stride,
    const float* __restrict__ scales, long s_stride,
    void* __restrict__ outp, int K, int N, int row_stride_e) {
  __shared__ uint16_t As[64 * 128];   // 16 KB
  __shared__ uint16_t Bs[128 * 128];  // 32 KB  [16][128][8]
  __shared__ int rowid_s[64];

  int e = blockIdx.z, mb = blockIdx.y, bn = blockIdx.x;
  int tid = threadIdx.x;
  int wave = tid >> 6, lane = tid & 63;

  int row_base = e * row_stride_e + mb * 64;
  int valid = 64;
  if (counts) {
    valid = counts[e] - mb * 64;
    if (valid <= 0) return;
    if (valid > 64) valid = 64;
  }
  if (tid < 64) {
    int rr = tid < valid ? tid : valid - 1;
    rowid_s[tid] = rowids ? rowids[row_base + rr] : row_base + rr;
  }

  const int* packed_e = packed + (long)e * p_stride;
  const float* scales_e = scales + (long)e * s_stride;

  int j = tid >> 1;        // B tile row (n)
  int wseg = tid & 1;      // which 8-word half of the 16-word row segment
  int n_col = bn * 128 + j;
  const int* prow = packed_e + (long)n_col * (K >> 3) + wseg * 8;

  f32x4 acc[2][4];
#pragma unroll
  for (int a0 = 0; a0 < 2; a0++)
#pragma unroll
    for (int b0 = 0; b0 < 4; b0++) {
      f32x4 z = {0.f, 0.f, 0.f, 0.f};
      acc[a0][b0] = z;
    }

  int wm = wave >> 1, wn = wave & 1;
  int q = lane >> 4;          // lane's k-chunk index within 32-k step
  int r16 = lane & 15;

  __syncthreads();  // rowid_s visible

  for (int kt = 0; kt < K; kt += 128) {
    // ---- stage A tile (64 rows x 128 k, bf16) via async global->LDS, 16B/lane.
    // dest chunk c of row r holds global chunk c ^ (r&15)
#pragma unroll
    for (int ii = 0; ii < 4; ii++) {
      int inst = wave * 4 + ii;
      int r = inst * 4 + (lane >> 4);
      int c = lane & 15;
      int g = c ^ (r & 15);
      const uint16_t* src = A + (long)rowid_s[r] * ldA + kt + (g << 3);
      __builtin_amdgcn_global_load_lds(
          (const __attribute__((address_space(1))) unsigned int*)src,
          (__attribute__((address_space(3))) unsigned int*)(As + inst * 512),
          16, 0, 0);
    }
    // ---- stage B tile: load 8 packed words, dequant via scaled byte-LUT + v_perm
    {
      float s = scales_e[(long)(kt >> 7) * N + n_col];
      uint32_t b1 = bf16rne(s), b15 = bf16rne(1.5f * s);
      uint32_t t0 = 0, t1 = b1 - 0x80, t2 = b1, t3 = b15;
      uint32_t t4 = b1 + 0x80, t5 = b15 + 0x80, t6 = b1 + 0x100, t7 = b15 + 0x100;
      uint32_t tll = (t0 & 0xFF) | ((t1 & 0xFF) << 8) | ((t2 & 0xFF) << 16) | ((t3 & 0xFF) << 24);
      uint32_t tlh = (t4 & 0xFF) | ((t5 & 0xFF) << 8) | ((t6 & 0xFF) << 16) | ((t7 & 0xFF) << 24);
      uint32_t thl = (t0 >> 8) | ((t1 >> 8) << 8) | ((t2 >> 8) << 16) | ((t3 >> 8) << 24);
      uint32_t thh = (t4 >> 8) | ((t5 >> 8) << 8) | ((t6 >> 8) << 16) | ((t7 >> 8) << 24);

      const int4* pv = (const int4*)(prow + (kt >> 3));
      int4 wA = pv[0];
      int4 wB = pv[1];
      uint32_t wsv[8] = {(uint32_t)wA.x, (uint32_t)wA.y, (uint32_t)wA.z, (uint32_t)wA.w,
                         (uint32_t)wB.x, (uint32_t)wB.y, (uint32_t)wB.z, (uint32_t)wB.w};
      // word i covers k-chunk kc = wseg*8 + i; dest offset = (kc*128 + j)*8 elems
      uint16_t* bdst = Bs + ((long)(wseg * 8) * 128 + j) * 8;
#pragma unroll
      for (int i = 0; i < 8; i++) {
        uint32_t w = wsv[i];
        uint32_t ev = w & 0x07070707u;         // mags of nibbles 0,2,4,6
        uint32_t od = (w >> 4) & 0x07070707u;  // mags of nibbles 1,3,5,7
        uint32_t se = (w << 4) & 0x80808080u;  // signs (even) -> bit7 of byte
        uint32_t so = w & 0x80808080u;         // signs (odd)
        uint32_t he = __builtin_amdgcn_perm(thh, thl, ev) | se;
        uint32_t ho = __builtin_amdgcn_perm(thh, thl, od) | so;
        uint32_t le = __builtin_amdgcn_perm(tlh, tll, ev);
        uint32_t lo = __builtin_amdgcn_perm(tlh, tll, od);
        uint32_t v02 = __builtin_amdgcn_perm(he, le, 0x05010400u);  // bf16(n0),bf16(n2)
        uint32_t v46 = __builtin_amdgcn_perm(he, le, 0x07030602u);  // bf16(n4),bf16(n6)
        uint32_t v13 = __builtin_amdgcn_perm(ho, lo, 0x05010400u);  // bf16(n1),bf16(n3)
        uint32_t v57 = __builtin_amdgcn_perm(ho, lo, 0x07030602u);  // bf16(n5),bf16(n7)
        uint4 qv;
        qv.x = __builtin_amdgcn_perm(v13, v02, 0x05040100u);  // n0,n1
        qv.y = __builtin_amdgcn_perm(v13, v02, 0x07060302u);  // n2,n3
        qv.z = __builtin_amdgcn_perm(v57, v46, 0x05040100u);  // n4,n5
        qv.w = __builtin_amdgcn_perm(v57, v46, 0x07060302u);  // n6,n7
        *(uint4*)(bdst + (long)i * 1024) = qv;
      }
    }
    __syncthreads();

    // ---- MFMA compute
#pragma unroll
    for (int kk = 0; kk < 128; kk += 32) {
      int kc = (kk >> 3) + q;  // this lane's k-chunk
      short8 af[2], bfr[4];
#pragma unroll
      for (int fm = 0; fm < 2; fm++) {
        int m = wm * 32 + fm * 16 + r16;
        af[fm] = *(const short8*)(As + (long)m * 128 + ((kc ^ r16) << 3));
      }
#pragma unroll
      for (int fn = 0; fn < 4; fn++) {
        int n = wn * 64 + fn * 16 + r16;
        bfr[fn] = *(const short8*)(Bs + ((long)kc * 128 + n) * 8);
      }
#pragma unroll
      for (int fm = 0; fm < 2; fm++)
#pragma unroll
        for (int fn = 0; fn < 4; fn++)
          acc[fm][fn] = __builtin_amdgcn_mfma_f32_16x16x32_bf16(af[fm], bfr[fn], acc[fm][fn], 0, 0, 0);
    }
    __syncthreads();
  }

  // ---- epilogue: D mapping col=lane&15, row=(lane>>4)*4+reg (m89/m91-verified)
  int outr0 = row_base + wm * 32 + ((lane >> 4) << 2);
  int outc0 = bn * 128 + wn * 64 + (lane & 15);
#pragma unroll
  for (int fm = 0; fm < 2; fm++)
#pragma unroll
    for (int fn = 0; fn < 4; fn++) {
#pragma unroll
      for (int r = 0; r < 4; r++) {
        long row = outr0 + fm * 16 + r;
        long col = outc0 + fn * 16;
        float vv = acc[fm][fn][r];
        if (OUTF32) ((float*)outp)[row * N + col] = vv;
        else ((uint16_t*)outp)[row * N + col] = (uint16_t)bf16rne(vv);
      }
    }
}

// ---------------- h = silu(g) * u  (bf16, elementwise x8) ----------------
__global__ void silu_mul_kernel(const uint16_t* __restrict__ g, const uint16_t* __restrict__ u,
                                uint16_t* __restrict__ h, int n8) {
  int i = blockIdx.x * blockDim.x + threadIdx.x;
  if (i >= n8) return;
  uint4 gv = ((const uint4*)g)[i];
  uint4 uv = ((const uint4*)u)[i];
  uint32_t gw[4] = {gv.x, gv.y, gv.z, gv.w};
  uint32_t uw[4] = {uv.x, uv.y, uv.z, uv.w};
  uint32_t rw[4];
#pragma unroll
  for (int w = 0; w < 4; w++) {
    float g0 = bf16f(gw[w] & 0xFFFFu), g1 = bf16f(gw[w] >> 16);
    float u0 = bf16f(uw[w] & 0xFFFFu), u1 = bf16f(uw[w] >> 16);
    float r0 = g0 / (1.f + __expf(-g0)) * u0;
    float r1 = g1 / (1.f + __expf(-g1)) * u1;
    rw[w] = bf16rne(r0) | (bf16rne(r1) << 16);
  }
  uint4 res; res.x = rw[0]; res.y = rw[1]; res.z = rw[2]; res.w = rw[3];
  ((uint4*)h)[i] = res;
}

// ---------------- combine: y[t] += sum_k w_k * eout[slot_k] ----------------
__global__ __launch_bounds__(256) void combine_kernel(
    float* __restrict__ y, const uint16_t* __restrict__ eout,
    const int* __restrict__ slot_of, const float* __restrict__ tw) {
  int t = blockIdx.x;
  int c = threadIdx.x * 8;
  float* yp = y + (long)t * H_ + c;
  float4 y0 = ((float4*)yp)[0];
  float4 y1 = ((float4*)yp)[1];
  float a[8] = {y0.x, y0.y, y0.z, y0.w, y1.x, y1.y, y1.z, y1.w};
#pragma unroll
  for (int k = 0; k < KTOP; k++) {
    int s = slot_of[t * KTOP + k];
    float w = tw[t * KTOP + k];
    if (s < 0) continue;
    uint4 v = *(const uint4*)(eout + (long)s * H_ + c);
    uint32_t vw[4] = {v.x, v.y, v.z, v.w};
#pragma unroll
    for (int jj = 0; jj < 4; jj++) {
      a[2 * jj]     += w * bf16f(vw[jj] & 0xFFFFu);
      a[2 * jj + 1] += w * bf16f(vw[jj] >> 16);
    }
  }
  float4 o0 = {a[0], a[1], a[2], a[3]};
  float4 o1 = {a[4], a[5], a[6], a[7]};
  ((float4*)yp)[0] = o0;
  ((float4*)yp)[1] = o1;
}

extern "C" void kernel_launch(void* const* d_in, const int* in_sizes, int n_in,
                              void* d_out, int out_size, void* d_ws, size_t ws_size,
                              hipStream_t stream) {
  const float* x              = (const float*)d_in[0];
  const float* gate_w         = (const float*)d_in[1];
  const float* gate_scales    = (const float*)d_in[2];
  const float* up_scales      = (const float*)d_in[3];
  const float* down_scales    = (const float*)d_in[4];
  const float* sh_gate_scales = (const float*)d_in[5];
  const float* sh_up_scales   = (const float*)d_in[6];
  const float* sh_down_scales = (const float*)d_in[7];
  const int* gate_packed      = (const int*)d_in[8];
  const int* up_packed        = (const int*)d_in[9];
  const int* down_packed      = (const int*)d_in[10];
  const int* sh_gate_packed   = (const int*)d_in[11];
  const int* sh_up_packed     = (const int*)d_in[12];
  const int* sh_down_packed   = (const int*)d_in[13];
  float* y = (float*)d_out;

  char* ws = (char*)d_ws;
  uint16_t* xb     = (uint16_t*)(ws);               // 4,194,304 B
  float*    tw     = (float*)(ws + 4194304);        // 16,384
  int*      ti     = (int*)(ws + 4210688);          // 16,384
  int*      counts = (int*)(ws + 4227072);          // 256
  int*      tlist  = (int*)(ws + 4227328);          // 32,768
  int*      slot_of= (int*)(ws + 4260096);          // 16,384
  uint16_t* gbuf   = (uint16_t*)(ws + 4276480);     // 25,165,824 (later h)
  uint16_t* ubuf   = (uint16_t*)(ws + 29442304);    // 25,165,824
  uint16_t* eout   = (uint16_t*)(ws + 29442304);    // 33,554,432 (aliases dead ubuf)
  uint16_t* gsbuf  = (uint16_t*)(ws + 62996736);    // 3,145,728 (later hs)
  uint16_t* usbuf  = (uint16_t*)(ws + 66142464);    // 3,145,728; end ~69.3 MB

  cast_x_kernel<<<2048, 256, 0, stream>>>(x, xb, T_ * H_ / 4);
  routing_kernel<<<T_, 256, 0, stream>>>(x, gate_w, tw, ti);
  assign_kernel<<<E_, 64, 0, stream>>>(ti, counts, tlist, slot_of);

  // expert gate / up : [<=128 tok] x [K=2048] -> [1536]
  gemm_fp4_kernel<0><<<dim3(12, 2, 64), 256, 0, stream>>>(
      xb, H_, tlist, counts, gate_packed, (long)I_ * (H_ / 8), gate_scales, (long)(H_ / GS_) * I_,
      gbuf, H_, I_, CAP);
  gemm_fp4_kernel<0><<<dim3(12, 2, 64), 256, 0, stream>>>(
      xb, H_, tlist, counts, up_packed, (long)I_ * (H_ / 8), up_scales, (long)(H_ / GS_) * I_,
      ubuf, H_, I_, CAP);
  silu_mul_kernel<<<(E_ * CAP * I_ / 8 + 255) / 256, 256, 0, stream>>>(
      gbuf, ubuf, gbuf, E_ * CAP * I_ / 8);
  // expert down : [<=128 tok] x [K=1536] -> [2048]
  gemm_fp4_kernel<0><<<dim3(16, 2, 64), 256, 0, stream>>>(
      gbuf, I_, nullptr, counts, down_packed, (long)H_ * (I_ / 8), down_scales, (long)(I_ / GS_) * H_,
      eout, I_, H_, CAP);

  // shared expert
  gemm_fp4_kernel<0><<<dim3(12, 16, 1), 256, 0, stream>>>(
      xb, H_, nullptr, nullptr, sh_gate_packed, 0, sh_gate_scales, 0,
      gsbuf, H_, I_, 0);
  gemm_fp4_kernel<0><<<dim3(12, 16, 1), 256, 0, stream>>>(
      xb, H_, nullptr, nullptr, sh_up_packed, 0, sh_up_scales, 0,
      usbuf, H_, I_, 0);
  silu_mul_kernel<<<(T_ * I_ / 8 + 255) / 256, 256, 0, stream>>>(
      gsbuf, usbuf, gsbuf, T_ * I_ / 8);
  gemm_fp4_kernel<1><<<dim3(16, 16, 1), 256, 0, stream>>>(
      gsbuf, I_, nullptr, nullptr, sh_down_packed, 0, sh_down_scales, 0,
      y, I_, H_, 0);

  combine_kernel<<<T_, 256, 0, stream>>>(y, eout, slot_of, tw);
}

// Round 3
// 645.472 us; speedup vs baseline: 1.9065x; 1.1105x over previous
//
#include <hip/hip_runtime.h>
#include <stdint.h>

#define E_ 64
#define KTOP 4
#define H_ 2048
#define I_ 1536
#define GS_ 128
#define T_ 1024
#define CAP 128

typedef __attribute__((ext_vector_type(8))) short short8;
typedef __attribute__((ext_vector_type(4))) float f32x4;

__device__ __forceinline__ uint32_t bf16rne(float f) {
  uint32_t u = __float_as_uint(f);
  return (u + 0x7FFFu + ((u >> 16) & 1u)) >> 16;
}
__device__ __forceinline__ float bf16f(uint32_t b) {
  return __uint_as_float(b << 16);
}

// ---------------- cast x (f32 -> bf16) ----------------
__global__ void cast_x_kernel(const float* __restrict__ x, uint16_t* __restrict__ xb, int n4) {
  int i = blockIdx.x * blockDim.x + threadIdx.x;
  if (i >= n4) return;
  float4 v = ((const float4*)x)[i];
  uint32_t lo = bf16rne(v.x) | (bf16rne(v.y) << 16);
  uint32_t hi = bf16rne(v.z) | (bf16rne(v.w) << 16);
  uint2 r; r.x = lo; r.y = hi;
  ((uint2*)xb)[i] = r;
}

// ---------------- transpose gate_w [E][H] -> gwT [H][E] ----------------
__global__ void transpose_gw_kernel(const float* __restrict__ gw, float* __restrict__ gwT) {
  int o = blockIdx.x * 256 + threadIdx.x;  // 131072
  int k = o >> 6, e = o & 63;
  gwT[o] = gw[(long)e * H_ + k];
}

// ---------------- routing: coalesced logits via gwT, then top-4 ----------------
__global__ __launch_bounds__(256) void routing_kernel(
    const float* __restrict__ x, const float* __restrict__ gwT,
    float* __restrict__ tw, int* __restrict__ ti) {
  int t = blockIdx.x;
  int tid = threadIdx.x;
  __shared__ float xs[H_];
  __shared__ float lgp[4][E_];
  const float4* xp = (const float4*)(x + (long)t * H_);
  ((float4*)xs)[tid] = xp[tid];
  ((float4*)xs)[tid + 256] = xp[tid + 256];
  __syncthreads();
  int e = tid & 63, w4 = tid >> 6;  // wave w4 covers k in [w4*512, w4*512+512)
  const float* gp = gwT + (long)w4 * 512 * E_ + e;
  const float* xw = xs + w4 * 512;
  float a0 = 0.f, a1 = 0.f, a2 = 0.f, a3 = 0.f;
#pragma unroll 4
  for (int k = 0; k < 512; k += 4) {
    a0 += xw[k]     * gp[(long)(k)     * E_];
    a1 += xw[k + 1] * gp[(long)(k + 1) * E_];
    a2 += xw[k + 2] * gp[(long)(k + 2) * E_];
    a3 += xw[k + 3] * gp[(long)(k + 3) * E_];
  }
  lgp[w4][e] = (a0 + a1) + (a2 + a3);
  __syncthreads();
  if (tid < 64) {
    int lane = tid;
    float v = lgp[0][lane] + lgp[1][lane] + lgp[2][lane] + lgp[3][lane];
    float vals[KTOP]; int ids[KTOP];
#pragma unroll
    for (int k = 0; k < KTOP; k++) {
      float bv = v; int bi = lane;
      for (int off = 32; off; off >>= 1) {
        float ov = __shfl_xor(bv, off);
        int oi = __shfl_xor(bi, off);
        if (ov > bv || (ov == bv && oi < bi)) { bv = ov; bi = oi; }
      }
      vals[k] = bv; ids[k] = bi;
      if (lane == bi) v = -3.4e38f;
    }
    if (lane == 0) {
      float m = vals[0];
      float p[KTOP]; float s = 0.f;
#pragma unroll
      for (int k = 0; k < KTOP; k++) { p[k] = expf(vals[k] - m); s += p[k]; }
      float inv = 1.f / s;
#pragma unroll
      for (int k = 0; k < KTOP; k++) {
        tw[t * KTOP + k] = p[k] * inv;
        ti[t * KTOP + k] = ids[k];
      }
    }
  }
}

// ---------------- dispatch: stable rank-within-expert + capacity ----------------
__global__ void assign_kernel(const int* __restrict__ ti, int* __restrict__ counts,
                              int* __restrict__ tlist, int* __restrict__ slot_of) {
  int e = blockIdx.x;
  int lane = threadIdx.x;  // 64
  int cnt = 0;
  for (int base = 0; base < T_ * KTOP; base += 64) {
    int a = base + lane;
    int ef = ti[a];
    unsigned long long m = __ballot(ef == e);
    if (ef == e) {
      int rank = cnt + __popcll(m & ((1ull << lane) - 1ull));
      if (rank < CAP) {
        tlist[e * CAP + rank] = a >> 2;
        slot_of[a] = e * CAP + rank;
      } else {
        slot_of[a] = -1;
      }
    }
    cnt += __popcll(m);
  }
  if (lane == 0) counts[e] = min(cnt, CAP);
}

// ---------------- generic FP4-dequant GEMM ----------------
// out[row_base+m, bn*128+n] = sum_k A[rowid(m), k] * W[n, k]
// tiles: M=128, N=128, BK=128 (=GS). 256 threads = 4 waves (2x2), wave tile 64x64.
// LDS (conflict-free for b128: 8 lanes per 16B-bank-group per instr):
//  As: 128x128 bf16, chunk c of row m holds global chunk c^(m&15) (XOR swizzle).
//  Bs: fragment-order [kc=k/8][n=0..127][8].
template <int OUTF32>
__global__ __launch_bounds__(256, 2) void gemm_fp4_kernel(
    const uint16_t* __restrict__ A, int ldA,
    const int* __restrict__ rowids, const int* __restrict__ counts,
    const int* __restrict__ packed, long p_stride,
    const float* __restrict__ scales, long s_stride,
    void* __restrict__ outp, int K, int N, int row_stride_e) {
  __shared__ uint16_t As[128 * 128];     // 32 KB
  __shared__ uint16_t Bs[16 * 128 * 8];  // 32 KB
  __shared__ int rowid_s[128];

  int e = blockIdx.z, mb = blockIdx.y, bn = blockIdx.x;
  int tid = threadIdx.x;
  int wave = tid >> 6, lane = tid & 63;

  int row_base = e * row_stride_e + mb * 128;
  int valid = 128;
  if (counts) {
    valid = counts[e] - mb * 128;
    if (valid <= 0) return;
    if (valid > 128) valid = 128;
  }
  if (tid < 128) {
    int rr = tid < valid ? tid : valid - 1;
    rowid_s[tid] = rowids ? rowids[row_base + rr] : row_base + rr;
  }

  const int* packed_e = packed + (long)e * p_stride;
  const float* scales_e = scales + (long)e * s_stride;

  int j = tid >> 1;        // B tile row (n) 0..127
  int wseg = tid & 1;      // which 8-word half of the 16-word row
  int n_col = bn * 128 + j;
  const int* prow = packed_e + (long)n_col * (K >> 3) + wseg * 8;

  f32x4 acc[4][4];
#pragma unroll
  for (int a0 = 0; a0 < 4; a0++)
#pragma unroll
    for (int b0 = 0; b0 < 4; b0++) {
      f32x4 z = {0.f, 0.f, 0.f, 0.f};
      acc[a0][b0] = z;
    }

  int wm = wave >> 1, wn = wave & 1;
  int q = lane >> 4;       // k-chunk quad within 32-k step
  int r16 = lane & 15;

  __syncthreads();  // rowid_s visible

  for (int kt = 0; kt < K; kt += 128) {
    // ---- stage A tile (128 rows x 128 k) async, 16B/lane; chunk XOR swizzle
#pragma unroll
    for (int ii = 0; ii < 8; ii++) {
      int inst = wave * 8 + ii;            // 0..31, covers rows inst*4..+4
      int r = inst * 4 + (lane >> 4);
      int c = lane & 15;
      int g = c ^ (r & 15);
      const uint16_t* src = A + (long)rowid_s[r] * ldA + kt + (g << 3);
      __builtin_amdgcn_global_load_lds(
          (const __attribute__((address_space(1))) unsigned int*)src,
          (__attribute__((address_space(3))) unsigned int*)(As + inst * 512),
          16, 0, 0);
    }
    // ---- stage B tile: 8 packed words/thread, dequant via scaled byte-LUT + v_perm
    {
      float s = scales_e[(long)(kt >> 7) * N + n_col];
      uint32_t b1 = bf16rne(s), b15 = bf16rne(1.5f * s);
      uint32_t t0 = 0, t1 = b1 - 0x80, t2 = b1, t3 = b15;
      uint32_t t4 = b1 + 0x80, t5 = b15 + 0x80, t6 = b1 + 0x100, t7 = b15 + 0x100;
      uint32_t tll = (t0 & 0xFF) | ((t1 & 0xFF) << 8) | ((t2 & 0xFF) << 16) | ((t3 & 0xFF) << 24);
      uint32_t tlh = (t4 & 0xFF) | ((t5 & 0xFF) << 8) | ((t6 & 0xFF) << 16) | ((t7 & 0xFF) << 24);
      uint32_t thl = (t0 >> 8) | ((t1 >> 8) << 8) | ((t2 >> 8) << 16) | ((t3 >> 8) << 24);
      uint32_t thh = (t4 >> 8) | ((t5 >> 8) << 8) | ((t6 >> 8) << 16) | ((t7 >> 8) << 24);

      const int4* pv = (const int4*)(prow + (kt >> 3));
      int4 wA = pv[0];
      int4 wB = pv[1];
      uint32_t wsv[8] = {(uint32_t)wA.x, (uint32_t)wA.y, (uint32_t)wA.z, (uint32_t)wA.w,
                         (uint32_t)wB.x, (uint32_t)wB.y, (uint32_t)wB.z, (uint32_t)wB.w};
      // word i covers k-chunk kc = wseg*8 + i; dest = ((kc*128)+j)*8 elems
      uint16_t* bdst = Bs + ((long)(wseg * 8) * 128 + j) * 8;
#pragma unroll
      for (int i = 0; i < 8; i++) {
        uint32_t w = wsv[i];
        uint32_t ev = w & 0x07070707u;
        uint32_t od = (w >> 4) & 0x07070707u;
        uint32_t se = (w << 4) & 0x80808080u;
        uint32_t so = w & 0x80808080u;
        uint32_t he = __builtin_amdgcn_perm(thh, thl, ev) | se;
        uint32_t ho = __builtin_amdgcn_perm(thh, thl, od) | so;
        uint32_t le = __builtin_amdgcn_perm(tlh, tll, ev);
        uint32_t lo = __builtin_amdgcn_perm(tlh, tll, od);
        uint32_t v02 = __builtin_amdgcn_perm(he, le, 0x05010400u);
        uint32_t v46 = __builtin_amdgcn_perm(he, le, 0x07030602u);
        uint32_t v13 = __builtin_amdgcn_perm(ho, lo, 0x05010400u);
        uint32_t v57 = __builtin_amdgcn_perm(ho, lo, 0x07030602u);
        uint4 qv;
        qv.x = __builtin_amdgcn_perm(v13, v02, 0x05040100u);
        qv.y = __builtin_amdgcn_perm(v13, v02, 0x07060302u);
        qv.z = __builtin_amdgcn_perm(v57, v46, 0x05040100u);
        qv.w = __builtin_amdgcn_perm(v57, v46, 0x07060302u);
        *(uint4*)(bdst + (long)i * 1024) = qv;
      }
    }
    __syncthreads();

    // ---- MFMA compute: wave tile 64x64, 4x4 of 16x16x32
#pragma unroll
    for (int kk = 0; kk < 128; kk += 32) {
      int kc = (kk >> 3) + q;
      short8 af[4], bfr[4];
#pragma unroll
      for (int fm = 0; fm < 4; fm++) {
        int m = wm * 64 + fm * 16 + r16;
        af[fm] = *(const short8*)(As + (long)m * 128 + ((kc ^ r16) << 3));
      }
#pragma unroll
      for (int fn = 0; fn < 4; fn++) {
        int n = wn * 64 + fn * 16 + r16;
        bfr[fn] = *(const short8*)(Bs + ((long)kc * 128 + n) * 8);
      }
#pragma unroll
      for (int fm = 0; fm < 4; fm++)
#pragma unroll
        for (int fn = 0; fn < 4; fn++)
          acc[fm][fn] = __builtin_amdgcn_mfma_f32_16x16x32_bf16(af[fm], bfr[fn], acc[fm][fn], 0, 0, 0);
    }
    __syncthreads();
  }

  // ---- epilogue: D mapping col=lane&15, row=(lane>>4)*4+reg
  int outr0 = wm * 64 + (q << 2);
  int outc0 = bn * 128 + wn * 64 + r16;
#pragma unroll
  for (int fm = 0; fm < 4; fm++)
#pragma unroll
    for (int fn = 0; fn < 4; fn++) {
#pragma unroll
      for (int r = 0; r < 4; r++) {
        int rloc = outr0 + fm * 16 + r;
        if (rloc >= valid) continue;
        long row = row_base + rloc;
        long col = outc0 + fn * 16;
        float vv = acc[fm][fn][r];
        if (OUTF32) ((float*)outp)[row * N + col] = vv;
        else ((uint16_t*)outp)[row * N + col] = (uint16_t)bf16rne(vv);
      }
    }
}

// ---------------- h = silu(g) * u  (bf16, elementwise x8) ----------------
__global__ void silu_mul_kernel(const uint16_t* __restrict__ g, const uint16_t* __restrict__ u,
                                uint16_t* __restrict__ h, int n8) {
  int i = blockIdx.x * blockDim.x + threadIdx.x;
  if (i >= n8) return;
  uint4 gv = ((const uint4*)g)[i];
  uint4 uv = ((const uint4*)u)[i];
  uint32_t gw[4] = {gv.x, gv.y, gv.z, gv.w};
  uint32_t uw[4] = {uv.x, uv.y, uv.z, uv.w};
  uint32_t rw[4];
#pragma unroll
  for (int w = 0; w < 4; w++) {
    float g0 = bf16f(gw[w] & 0xFFFFu), g1 = bf16f(gw[w] >> 16);
    float u0 = bf16f(uw[w] & 0xFFFFu), u1 = bf16f(uw[w] >> 16);
    float r0 = g0 / (1.f + __expf(-g0)) * u0;
    float r1 = g1 / (1.f + __expf(-g1)) * u1;
    rw[w] = bf16rne(r0) | (bf16rne(r1) << 16);
  }
  uint4 res; res.x = rw[0]; res.y = rw[1]; res.z = rw[2]; res.w = rw[3];
  ((uint4*)h)[i] = res;
}

// ---------------- combine: y[t] += sum_k w_k * eout[slot_k] ----------------
__global__ __launch_bounds__(256) void combine_kernel(
    float* __restrict__ y, const uint16_t* __restrict__ eout,
    const int* __restrict__ slot_of, const float* __restrict__ tw) {
  int t = blockIdx.x;
  int c = threadIdx.x * 8;
  float* yp = y + (long)t * H_ + c;
  float4 y0 = ((float4*)yp)[0];
  float4 y1 = ((float4*)yp)[1];
  float a[8] = {y0.x, y0.y, y0.z, y0.w, y1.x, y1.y, y1.z, y1.w};
#pragma unroll
  for (int k = 0; k < KTOP; k++) {
    int s = slot_of[t * KTOP + k];
    float w = tw[t * KTOP + k];
    if (s < 0) continue;
    uint4 v = *(const uint4*)(eout + (long)s * H_ + c);
    uint32_t vw[4] = {v.x, v.y, v.z, v.w};
#pragma unroll
    for (int jj = 0; jj < 4; jj++) {
      a[2 * jj]     += w * bf16f(vw[jj] & 0xFFFFu);
      a[2 * jj + 1] += w * bf16f(vw[jj] >> 16);
    }
  }
  float4 o0 = {a[0], a[1], a[2], a[3]};
  float4 o1 = {a[4], a[5], a[6], a[7]};
  ((float4*)yp)[0] = o0;
  ((float4*)yp)[1] = o1;
}

extern "C" void kernel_launch(void* const* d_in, const int* in_sizes, int n_in,
                              void* d_out, int out_size, void* d_ws, size_t ws_size,
                              hipStream_t stream) {
  const float* x              = (const float*)d_in[0];
  const float* gate_w         = (const float*)d_in[1];
  const float* gate_scales    = (const float*)d_in[2];
  const float* up_scales      = (const float*)d_in[3];
  const float* down_scales    = (const float*)d_in[4];
  const float* sh_gate_scales = (const float*)d_in[5];
  const float* sh_up_scales   = (const float*)d_in[6];
  const float* sh_down_scales = (const float*)d_in[7];
  const int* gate_packed      = (const int*)d_in[8];
  const int* up_packed        = (const int*)d_in[9];
  const int* down_packed      = (const int*)d_in[10];
  const int* sh_gate_packed   = (const int*)d_in[11];
  const int* sh_up_packed     = (const int*)d_in[12];
  const int* sh_down_packed   = (const int*)d_in[13];
  float* y = (float*)d_out;

  char* ws = (char*)d_ws;
  uint16_t* xb     = (uint16_t*)(ws);               // 4,194,304 B
  float*    tw     = (float*)(ws + 4194304);
  int*      ti     = (int*)(ws + 4210688);
  int*      counts = (int*)(ws + 4227072);
  int*      tlist  = (int*)(ws + 4227328);
  int*      slot_of= (int*)(ws + 4260096);
  uint16_t* gbuf   = (uint16_t*)(ws + 4276480);     // 25,165,824 (later h)
  float*    gwT    = (float*)(ws + 4276480);        // 524,288 B, aliases gbuf (dead before gate GEMM)
  uint16_t* ubuf   = (uint16_t*)(ws + 29442304);    // 25,165,824
  uint16_t* eout   = (uint16_t*)(ws + 29442304);    // 33,554,432 (aliases dead ubuf)
  uint16_t* gsbuf  = (uint16_t*)(ws + 62996736);    // 3,145,728 (later hs)
  uint16_t* usbuf  = (uint16_t*)(ws + 66142464);    // 3,145,728; end ~69.3 MB

  cast_x_kernel<<<2048, 256, 0, stream>>>(x, xb, T_ * H_ / 4);
  transpose_gw_kernel<<<512, 256, 0, stream>>>(gate_w, gwT);
  routing_kernel<<<T_, 256, 0, stream>>>(x, gwT, tw, ti);
  assign_kernel<<<E_, 64, 0, stream>>>(ti, counts, tlist, slot_of);

  // expert gate / up : [<=128 tok] x [K=2048] -> [1536]
  gemm_fp4_kernel<0><<<dim3(12, 1, 64), 256, 0, stream>>>(
      xb, H_, tlist, counts, gate_packed, (long)I_ * (H_ / 8), gate_scales, (long)(H_ / GS_) * I_,
      gbuf, H_, I_, CAP);
  gemm_fp4_kernel<0><<<dim3(12, 1, 64), 256, 0, stream>>>(
      xb, H_, tlist, counts, up_packed, (long)I_ * (H_ / 8), up_scales, (long)(H_ / GS_) * I_,
      ubuf, H_, I_, CAP);
  silu_mul_kernel<<<(E_ * CAP * I_ / 8 + 255) / 256, 256, 0, stream>>>(
      gbuf, ubuf, gbuf, E_ * CAP * I_ / 8);
  // expert down : [<=128 tok] x [K=1536] -> [2048]
  gemm_fp4_kernel<0><<<dim3(16, 1, 64), 256, 0, stream>>>(
      gbuf, I_, nullptr, counts, down_packed, (long)H_ * (I_ / 8), down_scales, (long)(I_ / GS_) * H_,
      eout, I_, H_, CAP);

  // shared expert (M=1024 -> mb=8)
  gemm_fp4_kernel<0><<<dim3(12, 8, 1), 256, 0, stream>>>(
      xb, H_, nullptr, nullptr, sh_gate_packed, 0, sh_gate_scales, 0,
      gsbuf, H_, I_, 0);
  gemm_fp4_kernel<0><<<dim3(12, 8, 1), 256, 0, stream>>>(
      xb, H_, nullptr, nullptr, sh_up_packed, 0, sh_up_scales, 0,
      usbuf, H_, I_, 0);
  silu_mul_kernel<<<(T_ * I_ / 8 + 255) / 256, 256, 0, stream>>>(
      gsbuf, usbuf, gsbuf, T_ * I_ / 8);
  gemm_fp4_kernel<1><<<dim3(16, 8, 1), 256, 0, stream>>>(
      gsbuf, I_, nullptr, nullptr, sh_down_packed, 0, sh_down_scales, 0,
      y, I_, H_, 0);

  combine_kernel<<<T_, 256, 0, stream>>>(y, eout, slot_of, tw);
}